// Round 10
// baseline (624.252 us; speedup 1.0000x reference)
//
#include <hip/hip_runtime.h>

#define HD 128  // hidden/feature dim (fixed by problem)

typedef _Float16 f16x8 __attribute__((ext_vector_type(8)));
typedef _Float16 f16x2 __attribute__((ext_vector_type(2)));
typedef float f32x4 __attribute__((ext_vector_type(4)));

// sparse role (role=1) occupies every k-th block: positions q*k, q<S.
__device__ __forceinline__ void role_map(int bi, int S, int k, int& role, int& rid) {
  int q = bi / k, rem = bi - q * k;
  if (rem == 0 && q < S) { role = 1; rid = q; }
  else { role = 0; int na = q + (rem ? 1 : 0); if (na > S) na = S; rid = bi - na; }
}

// ---------------- weight convert: fp32 [k][n] -> f16 MFMA-fragment order ----------
// per matrix 16384 halves at [((nt*4+kc)*64 + 16*q + n16)*8 + j]; 32 blocks total.
__global__ void k_wcvt(const float* __restrict__ w0, const float* __restrict__ w1,
                       const float* __restrict__ w2, const float* __restrict__ w3,
                       _Float16* __restrict__ Wf) {
  int m = blockIdx.x >> 3;
  const float* Wg = (m == 0) ? w0 : (m == 1) ? w1 : (m == 2) ? w2 : w3;
  int idx0 = (blockIdx.x & 7) * 2048 + threadIdx.x * 8;
  float4 u0 = *(const float4*)(Wg + idx0);
  float4 u1 = *(const float4*)(Wg + idx0 + 4);
  int k = idx0 >> 7, n0 = idx0 & 127;
  int kc = k >> 5, q2 = (k >> 3) & 3, j = k & 7;
  _Float16* dst = Wf + (size_t)m * 16384;
  float vv[8] = {u0.x, u0.y, u0.z, u0.w, u1.x, u1.y, u1.z, u1.w};
  #pragma unroll
  for (int d = 0; d < 8; ++d) {
    int n = n0 + d;
    dst[(size_t)(((n >> 4) * 4 + kc) * 64 + 16 * q2 + (n & 15)) * 8 + j] = (_Float16)vv[d];
  }
}

// ---------------- deg+slot role (atomic-rate-bound) ----------------
__device__ __forceinline__ void deg_core(int rid, int degB,
    const int* __restrict__ ei0, const int* __restrict__ ei1, int E, int N,
    int* __restrict__ deg2, unsigned short* __restrict__ slot) {
  int g = (rid >= degB);
  int cb = rid - g * degB;
  const int* rows = g ? ei1 : ei0;
  int* deg = deg2 + g * N;
  unsigned short* sl = slot + (size_t)g * E;
  int base = (cb * 256 + threadIdx.x) * 4;
  if (base + 3 < E) {
    int4 r = *(const int4*)(rows + base);
    union { unsigned short us[4]; uint2 v; } s;
    s.us[0] = (unsigned short)atomicAdd(&deg[r.x], 1);
    s.us[1] = (unsigned short)atomicAdd(&deg[r.y], 1);
    s.us[2] = (unsigned short)atomicAdd(&deg[r.z], 1);
    s.us[3] = (unsigned short)atomicAdd(&deg[r.w], 1);
    *(uint2*)(sl + base) = s.v;
  } else {
    for (int e = base; e < E; ++e)
      sl[e] = (unsigned short)atomicAdd(&deg[rows[e]], 1);
  }
}

// ---------------- CSR fill role (atomic-free; lazy offs) ----------------
__device__ __forceinline__ void fill_core(int rid, int g,
    const int* __restrict__ ei0, const int* __restrict__ ei1, int E, int N,
    const int* __restrict__ offs, const int* __restrict__ partials,
    const unsigned short* __restrict__ slot, unsigned short* __restrict__ csr_col) {
  const int* eg = (g ? ei1 : ei0);
  const int* ob = offs + g * N;
  const unsigned short* sl = slot + (size_t)g * E;
  int gN = g * N;
  int base = (rid * 256 + threadIdx.x) * 4;
  if (base + 3 < E) {
    int4 r = *(const int4*)(eg + base);
    int4 c = *(const int4*)(eg + E + base);
    uint2 sv = *(const uint2*)(sl + base);
    csr_col[ob[r.x] + partials[(gN + r.x) >> 8] + (sv.x & 0xffff)] = (unsigned short)c.x;
    csr_col[ob[r.y] + partials[(gN + r.y) >> 8] + (sv.x >> 16)]    = (unsigned short)c.y;
    csr_col[ob[r.z] + partials[(gN + r.z) >> 8] + (sv.y & 0xffff)] = (unsigned short)c.z;
    csr_col[ob[r.w] + partials[(gN + r.w) >> 8] + (sv.y >> 16)]    = (unsigned short)c.w;
  } else {
    for (int e = base; e < E; ++e)
      csr_col[ob[eg[e]] + partials[(gN + eg[e]) >> 8] + sl[e]] = (unsigned short)eg[E + e];
  }
}

// ---------------- GEMM role: C = (A @ Wfrag + b) (*dis[row]) ----------------
// block = 128 rows (4 waves x 32); W staged LDS (conflict-free b128 copy).
template<bool RELU, bool SCALE>
__device__ __forceinline__ void gemm_core(_Float16* lds, int bi, int rowOff,
    const _Float16* __restrict__ Ab, const _Float16* __restrict__ Wf,
    const float* __restrict__ bias, const float* __restrict__ scale,
    _Float16* __restrict__ C, int Ntot) {
  const int tid = threadIdx.x;
  #pragma unroll
  for (int i = 0; i < 8; ++i)
    *(float4*)&lds[tid * 8 + i * 2048] = *(const float4*)&Wf[tid * 8 + i * 2048];
  __syncthreads();

  const int lane = tid & 63, wave = tid >> 6;
  const int n16 = lane & 15, q = lane >> 4;
  const int rowbase = rowOff + bi * 128 + wave * 32;

  int arow[2];
  #pragma unroll
  for (int t = 0; t < 2; ++t) {
    int r = rowbase + 16 * t + n16;
    arow[t] = (r < Ntot) ? r : (Ntot - 1);
  }
  f32x4 acc[2][8];
  #pragma unroll
  for (int t = 0; t < 2; ++t)
    #pragma unroll
    for (int nt = 0; nt < 8; ++nt) acc[t][nt] = (f32x4){0.f, 0.f, 0.f, 0.f};

  #pragma unroll
  for (int kc = 0; kc < 4; ++kc) {
    f16x8 a[2];
    #pragma unroll
    for (int t = 0; t < 2; ++t)
      a[t] = *(const f16x8*)(Ab + (size_t)arow[t] * HD + kc * 32 + q * 8);
    #pragma unroll
    for (int nt = 0; nt < 8; ++nt) {
      f16x8 b = *(const f16x8*)&lds[(size_t)((nt * 4 + kc) * 64 + lane) * 8];
      #pragma unroll
      for (int t = 0; t < 2; ++t)
        acc[t][nt] = __builtin_amdgcn_mfma_f32_16x16x32_f16(a[t], b, acc[t][nt], 0, 0, 0);
    }
  }
  float bv[8];
  #pragma unroll
  for (int nt = 0; nt < 8; ++nt) bv[nt] = bias[nt * 16 + n16];
  #pragma unroll
  for (int t = 0; t < 2; ++t) {
    #pragma unroll
    for (int r = 0; r < 4; ++r) {
      int row = rowbase + 16 * t + 4 * q + r;
      if (row < Ntot) {
        float s = SCALE ? scale[row] : 1.0f;
        #pragma unroll
        for (int nt = 0; nt < 8; ++nt) {
          float v = acc[t][nt][r] + bv[nt];
          if (RELU) v = fmaxf(v, 0.f);
          if (SCALE) v *= s;
          C[(size_t)row * HD + nt * 16 + n16] = (_Float16)v;
        }
      }
    }
  }
}

// ---------------- chained enc1+enc2 (row-local; act via wave-private LDS) ---------
// layer1: A fp32 x (CVT), B global Wf0 frags, relu -> LDS act (stride 136 f16,
// 2-way-conflict-free). layer2: A from LDS, B global Wf1 frags -> global H.
// No barriers: act tile is wave-private; in-wave LDS ops are ordered.
__device__ __forceinline__ void chain_core(_Float16* act, int bi,
    const float* __restrict__ x0, const float* __restrict__ x1,
    const _Float16* __restrict__ Wf0, const _Float16* __restrict__ Wf1,
    const float* __restrict__ b1, const float* __restrict__ b2,
    _Float16* __restrict__ H, int N, int Ntot) {
  const int tid = threadIdx.x;
  const int lane = tid & 63, wave = tid >> 6;
  const int n16 = lane & 15, q = lane >> 4;
  const int rowbase = bi * 128 + wave * 32;
  _Float16* wact = act + wave * 4352;   // 32 rows x 136 f16

  int arow[2];
  #pragma unroll
  for (int t = 0; t < 2; ++t) {
    int r = rowbase + 16 * t + n16;
    arow[t] = (r < Ntot) ? r : (Ntot - 1);
  }
  f32x4 acc[2][8];
  #pragma unroll
  for (int t = 0; t < 2; ++t)
    #pragma unroll
    for (int nt = 0; nt < 8; ++nt) acc[t][nt] = (f32x4){0.f, 0.f, 0.f, 0.f};

  // layer 1: x -> relu(x@W1+b1)
  #pragma unroll
  for (int kc = 0; kc < 4; ++kc) {
    f16x8 a[2];
    #pragma unroll
    for (int t = 0; t < 2; ++t) {
      int r = arow[t];
      const float* src = (r < N) ? (x0 + (size_t)r * HD) : (x1 + (size_t)(r - N) * HD);
      float4 u0 = *(const float4*)(src + kc * 32 + q * 8);
      float4 u1 = *(const float4*)(src + kc * 32 + q * 8 + 4);
      union { _Float16 h[8]; f16x8 v; } tmp;
      tmp.h[0] = (_Float16)u0.x; tmp.h[1] = (_Float16)u0.y;
      tmp.h[2] = (_Float16)u0.z; tmp.h[3] = (_Float16)u0.w;
      tmp.h[4] = (_Float16)u1.x; tmp.h[5] = (_Float16)u1.y;
      tmp.h[6] = (_Float16)u1.z; tmp.h[7] = (_Float16)u1.w;
      a[t] = tmp.v;
    }
    #pragma unroll
    for (int nt = 0; nt < 8; ++nt) {
      f16x8 b = *(const f16x8*)&Wf0[(size_t)((nt * 4 + kc) * 64 + lane) * 8];
      #pragma unroll
      for (int t = 0; t < 2; ++t)
        acc[t][nt] = __builtin_amdgcn_mfma_f32_16x16x32_f16(a[t], b, acc[t][nt], 0, 0, 0);
    }
  }
  {
    float bv[8];
    #pragma unroll
    for (int nt = 0; nt < 8; ++nt) bv[nt] = b1[nt * 16 + n16];
    #pragma unroll
    for (int t = 0; t < 2; ++t)
      #pragma unroll
      for (int r = 0; r < 4; ++r)
        #pragma unroll
        for (int nt = 0; nt < 8; ++nt)
          wact[(16 * t + 4 * q + r) * 136 + nt * 16 + n16] =
              (_Float16)fmaxf(acc[t][nt][r] + bv[nt], 0.f);
  }

  // layer 2: h1 -> h1@W2+b2 (no relu)
  #pragma unroll
  for (int t = 0; t < 2; ++t)
    #pragma unroll
    for (int nt = 0; nt < 8; ++nt) acc[t][nt] = (f32x4){0.f, 0.f, 0.f, 0.f};
  #pragma unroll
  for (int kc = 0; kc < 4; ++kc) {
    f16x8 a[2];
    #pragma unroll
    for (int t = 0; t < 2; ++t)
      a[t] = *(const f16x8*)&wact[(16 * t + n16) * 136 + kc * 32 + q * 8];
    #pragma unroll
    for (int nt = 0; nt < 8; ++nt) {
      f16x8 b = *(const f16x8*)&Wf1[(size_t)((nt * 4 + kc) * 64 + lane) * 8];
      #pragma unroll
      for (int t = 0; t < 2; ++t)
        acc[t][nt] = __builtin_amdgcn_mfma_f32_16x16x32_f16(a[t], b, acc[t][nt], 0, 0, 0);
    }
  }
  {
    float bv[8];
    #pragma unroll
    for (int nt = 0; nt < 8; ++nt) bv[nt] = b2[nt * 16 + n16];
    #pragma unroll
    for (int t = 0; t < 2; ++t)
      #pragma unroll
      for (int r = 0; r < 4; ++r) {
        int row = rowbase + 16 * t + 4 * q + r;
        if (row < Ntot)
          #pragma unroll
          for (int nt = 0; nt < 8; ++nt)
            H[(size_t)row * HD + nt * 16 + n16] = (_Float16)(acc[t][nt][r] + bv[nt]);
      }
  }
}

// ---------------- aggregate role: out[r] = relu(dis[r]*sum T[col]) ----------------
template<bool POOL>
__device__ __forceinline__ void agg_core(float* red, int rid, int nodeBase,
    const _Float16* __restrict__ T, const int* __restrict__ offs,
    const int* __restrict__ partials, const unsigned short* __restrict__ csr_col,
    const float* __restrict__ dis, _Float16* __restrict__ out,
    float* __restrict__ poolrep, int N, int Ntot, int Etot) {
  const int lane = threadIdx.x & 63;
  const int wave = threadIdx.x >> 6;
  const int gw = nodeBase + rid * 4 + wave;
  const int sub = lane >> 4, c16 = lane & 15;

  f16x2 hacc[4];
  #pragma unroll
  for (int j = 0; j < 4; ++j) hacc[j] = (f16x2){(_Float16)0.f, (_Float16)0.f};

  const int beg = offs[gw] + partials[gw >> 8];
  const int end = (gw + 1 == Ntot) ? Etot : (offs[gw + 1] + partials[(gw + 1) >> 8]);
  const uint4* Tg = (const uint4*)(T + (size_t)(gw >= N ? N : 0) * HD);
  for (int e = beg; e < end; e += 16) {
    uint4 v[4];
    #pragma unroll
    for (int gp = 0; gp < 4; ++gp) {
      v[gp] = make_uint4(0, 0, 0, 0);
      if (e + 4 * gp < end) {              // wave-uniform
        int eg = e + 4 * gp + sub;
        bool valid = (eg < end);
        int ce = valid ? eg : (end - 1);
        int col = csr_col[ce];
        uint4 tv = Tg[(size_t)col * 16 + c16];
        if (valid) v[gp] = tv;
      }
    }
    #pragma unroll
    for (int gp = 0; gp < 4; ++gp) {
      union { uint4 u; f16x2 h[4]; } w;
      w.u = v[gp];
      hacc[0] += w.h[0];
      hacc[1] += w.h[1];
      hacc[2] += w.h[2];
      hacc[3] += w.h[3];
    }
  }

  float ax[8];
  #pragma unroll
  for (int j = 0; j < 4; ++j) {
    ax[2 * j]     = (float)hacc[j][0];
    ax[2 * j + 1] = (float)hacc[j][1];
  }
  #pragma unroll
  for (int j = 0; j < 8; ++j) {
    ax[j] += __shfl_xor(ax[j], 32, 64);
    ax[j] += __shfl_xor(ax[j], 16, 64);
  }
  float dr = dis[gw];
  #pragma unroll
  for (int j = 0; j < 8; ++j) ax[j] = fmaxf(ax[j] * dr, 0.f);

  if (!POOL) {
    if (sub == 0) {
      union { uint4 u; _Float16 h[8]; } o;
      #pragma unroll
      for (int j = 0; j < 8; ++j) o.h[j] = (_Float16)ax[j];
      ((uint4*)out)[(size_t)gw * 16 + c16] = o.u;
    }
  } else {
    if (sub == 0) {
      *(float4*)&red[wave * 128 + c16 * 8]     = make_float4(ax[0], ax[1], ax[2], ax[3]);
      *(float4*)&red[wave * 128 + c16 * 8 + 4] = make_float4(ax[4], ax[5], ax[6], ax[7]);
    }
    __syncthreads();
    int t = threadIdx.x;
    if (t < 128) {
      float s = red[t] + red[128 + t] + red[256 + t] + red[384 + t];
      int g = (nodeBase >= N) ? 1 : 0;
      atomicAdd(&poolrep[(size_t)((rid & 15) * 2 + g) * 128 + t], s);
    }
  }
}

// ---------------- D1: deg_slot aux || chained enc1+enc2 ----------------
__global__ __launch_bounds__(256, 4) void k_d1(
    const float* __restrict__ x0, const float* __restrict__ x1,
    const _Float16* __restrict__ Wf, const float* __restrict__ b1,
    const float* __restrict__ b2, _Float16* __restrict__ H,
    const int* __restrict__ ei0, const int* __restrict__ ei1, int E, int N, int Ntot,
    int* __restrict__ deg2, unsigned short* __restrict__ slot, int G, int A, int degB) {
  __shared__ _Float16 act[4 * 4352];  // 34.8 KB
  int role, rid;
  role_map(blockIdx.x, G, (A + G) / G, role, rid);  // sparse = chain
  if (role == 1)
    chain_core(act, rid, x0, x1, Wf, Wf + 16384, b1, b2, H, N, Ntot);
  else
    deg_core(rid, degB, ei0, ei1, E, N, deg2, slot);
}

// ---------------- D2: per-block deg scan + dis; last block scans partials ---------
__global__ __launch_bounds__(256, 2) void k_scan(
    const int* __restrict__ deg2, int* __restrict__ offs, int* __restrict__ partials,
    float* __restrict__ dis, int Ntot, int scanB, int* __restrict__ ctr) {
  __shared__ int s[512];
  __shared__ int lastFlag;
  int rid = blockIdx.x, t = threadIdx.x;
  int i = rid * 256 + t;
  int v = (i < Ntot) ? deg2[i] : 0;
  s[t] = v;
  __syncthreads();
  #pragma unroll
  for (int off = 1; off < 256; off <<= 1) {
    int x = (t >= off) ? s[t - off] : 0;
    __syncthreads();
    s[t] += x;
    __syncthreads();
  }
  if (i < Ntot) {
    offs[i] = s[t] - v;
    dis[i] = (v > 0) ? (1.0f / sqrtf((float)v)) : 0.0f;
  }
  if (t == 255) partials[rid] = s[255];
  __syncthreads();
  if (t == 0) {
    __threadfence();
    lastFlag = (atomicAdd(ctr, 1) == scanB - 1);
  }
  __syncthreads();
  if (lastFlag) {
    __threadfence();
    volatile int* vp = partials;
    int P = scanB;
    int v0 = (t < P) ? vp[t] : 0;
    int v1 = (t + 256 < P) ? vp[t + 256] : 0;
    __syncthreads();
    s[t] = v0;
    s[t + 256] = v1;
    __syncthreads();
    #pragma unroll
    for (int off = 1; off < 256; off <<= 1) {
      int x0 = (t >= off) ? s[t - off] : 0;
      int x1 = (t >= off) ? s[256 + t - off] : 0;
      __syncthreads();
      s[t] += x0;
      s[256 + t] += x1;
      __syncthreads();
    }
    int tot0 = s[255];
    if (t < P) partials[t] = s[t] - v0;
    if (t + 256 < P) partials[t + 256] = s[256 + t] + tot0 - v1;
  }
}

// ---------------- D3: fill-g (sparse) || conv GEMM over Ntot rows ----------------
__global__ __launch_bounds__(256, 4) void k_gemm_fill(
    const _Float16* __restrict__ Ain, const _Float16* __restrict__ Wf,
    const float* __restrict__ bias, const float* __restrict__ dis,
    _Float16* __restrict__ Cout, int Ntot, int G,
    int fg, const int* __restrict__ ei0, const int* __restrict__ ei1, int E, int N,
    const int* __restrict__ offs, const int* __restrict__ partials,
    const unsigned short* __restrict__ slot, unsigned short* __restrict__ csr_col, int A) {
  __shared__ _Float16 lds[16384];
  int role, rid;
  role_map(blockIdx.x, A, (A + G) / A, role, rid);  // sparse = fill
  if (role == 1)
    fill_core(rid, fg, ei0, ei1, E, N, offs, partials, slot, csr_col);
  else
    gemm_core<false, true>(lds, rid, 0, Ain, Wf, bias, dis, Cout, Ntot);
}

// ---------------- D4: fill-g (sparse) || aggregate (no pool) ----------------
__global__ __launch_bounds__(256, 4) void k_agg_fill(
    const _Float16* __restrict__ T, const int* __restrict__ offs,
    const int* __restrict__ partials, const unsigned short* __restrict__ csr_col,
    const float* __restrict__ dis, _Float16* __restrict__ aggOut,
    int nodeBase, int N, int Ntot, int Etot, int nAgg,
    int fg, const int* __restrict__ ei0, const int* __restrict__ ei1, int E,
    const unsigned short* __restrict__ slot, unsigned short* __restrict__ csr_out, int A) {
  int role, rid;
  role_map(blockIdx.x, A, (nAgg + A) / A, role, rid);  // sparse = fill
  if (role == 1)
    fill_core(rid, fg, ei0, ei1, E, N, offs, partials, slot, csr_out);
  else
    agg_core<false>(nullptr, rid, nodeBase, T, offs, partials, csr_col, dis,
                    aggOut, nullptr, N, Ntot, Etot);
}

// ---------------- D5/D6: conv2 GEMM (sparse) || aggregate ----------------
template<bool POOL>
__global__ __launch_bounds__(256, 4) void k_agg_gemm(
    const _Float16* __restrict__ T, const int* __restrict__ offs,
    const int* __restrict__ partials, const unsigned short* __restrict__ csr_col,
    const float* __restrict__ dis, _Float16* __restrict__ aggOut,
    float* __restrict__ poolrep, int nodeBase, int N, int Ntot, int Etot, int nAgg,
    const _Float16* __restrict__ Ain, const _Float16* __restrict__ Wf,
    const float* __restrict__ bias, _Float16* __restrict__ Cout, int rowOff, int G) {
  __shared__ _Float16 lds[16384];
  int role, rid;
  role_map(blockIdx.x, G, (nAgg + G) / G, role, rid);  // sparse = gemm
  if (role == 1)
    gemm_core<false, true>(lds, rid, rowOff, Ain, Wf, bias, dis, Cout, Ntot);
  else
    agg_core<POOL>((float*)lds, rid, nodeBase, T, offs, partials, csr_col, dis,
                   aggOut, poolrep, N, Ntot, Etot);
}

// ---------------- D7: aggregate + pool standalone (small LDS, high occ) -----------
__global__ __launch_bounds__(256) void k_agg_pool(
    const _Float16* __restrict__ T, const int* __restrict__ offs,
    const int* __restrict__ partials, const unsigned short* __restrict__ csr_col,
    const float* __restrict__ dis, float* __restrict__ poolrep,
    int nodeBase, int N, int Ntot, int Etot) {
  __shared__ float red[512];
  agg_core<true>(red, blockIdx.x, nodeBase, T, offs, partials, csr_col, dis,
                 nullptr, poolrep, N, Ntot, Etot);
}

// ---------------- final similarity MLP (tiny, fp32) ----------------
__global__ void k_final(const float* __restrict__ poolrep,
                        const float* __restrict__ W1, const float* __restrict__ b1,
                        const float* __restrict__ W2, const float* __restrict__ b2,
                        float* __restrict__ out, float invN) {
  __shared__ float cs[512];
  __shared__ float red[2];
  int t = threadIdx.x;  // 128 threads
  float g1 = 0.f, g2 = 0.f;
  #pragma unroll
  for (int r = 0; r < 16; ++r) {
    g1 += poolrep[r * 256 + t];
    g2 += poolrep[r * 256 + 128 + t];
  }
  g1 *= invN;
  g2 *= invN;
  cs[t] = g1;
  cs[128 + t] = g2;
  cs[256 + t] = fabsf(g1 - g2);
  cs[384 + t] = g1 * g2;
  __syncthreads();
  float acc = b1[t];
  #pragma unroll 8
  for (int i = 0; i < 512; ++i) acc = fmaf(cs[i], W1[(size_t)i * HD + t], acc);
  float h = fmaxf(acc, 0.f);
  float v = h * W2[t];
  #pragma unroll
  for (int off = 32; off > 0; off >>= 1) v += __shfl_down(v, off, 64);
  if ((t & 63) == 0) red[t >> 6] = v;
  __syncthreads();
  if (t == 0) out[0] = red[0] + red[1] + b2[0];
}

extern "C" void kernel_launch(void* const* d_in, const int* in_sizes, int n_in,
                              void* d_out, int out_size, void* d_ws, size_t ws_size,
                              hipStream_t stream) {
  const float* x1     = (const float*)d_in[0];
  const int*   ei1    = (const int*)d_in[1];
  const float* x2     = (const float*)d_in[2];
  const int*   ei2    = (const int*)d_in[3];
  const float* W_in[4] = {(const float*)d_in[4], (const float*)d_in[6],
                          (const float*)d_in[8], (const float*)d_in[10]};
  const float* B_in[4] = {(const float*)d_in[5], (const float*)d_in[7],
                          (const float*)d_in[9], (const float*)d_in[11]};
  const float* sim_w1 = (const float*)d_in[12];
  const float* sim_b1 = (const float*)d_in[13];
  const float* sim_w2 = (const float*)d_in[14];
  const float* sim_b2 = (const float*)d_in[15];

  const int N = in_sizes[0] / HD;
  const int E = in_sizes[1] / 2;
  const int Ntot = 2 * N;

  // workspace layout (16B-aligned chunks first)
  _Float16* sp = (_Float16*)d_ws;
  _Float16* bufA = sp; sp += (size_t)Ntot * HD;   // H (enc2 out) -> later T2
  _Float16* bufB = sp; sp += (size_t)Ntot * HD;   // T1 (conv1 out)
  _Float16* bufC = sp; sp += (size_t)Ntot * HD;   // H1 (agg1 out)
  _Float16* WfB  = sp; sp += 4 * 16384;           // enc1,enc2,conv1,conv2 frag f16
  float* fp = (float*)sp;
  float* dis     = fp; fp += Ntot;
  float* poolrep = fp; fp += 16 * 256;            // zeroed with ctrs+deg2 (adjacent)
  int* ip = (int*)fp;
  int* ctrs     = ip; ip += 8;                    // [0]=pscan ctr
  int* deg2     = ip; ip += Ntot;
  int* offs     = ip; ip += Ntot;
  int* partials = ip; ip += 512;
  ip = (int*)(((uintptr_t)ip + 15) & ~(uintptr_t)15);
  unsigned short* slot = (unsigned short*)ip;       // 2E ushorts
  unsigned short* csr_col = slot + 2 * (size_t)E;   // 2E ushorts

  const int G1    = (Ntot + 127) / 128;             // 782 chain/conv1 blocks
  const int Gc    = (N + 127) / 128;                // 391 per-graph conv2 blocks
  const int scanB = (Ntot + 255) / 256;             // 391 (<=512 required)
  const int aggB  = N / 4;                          // 12500 per graph (N%4==0)
  const int degB  = ((E + 3) / 4 + 255) / 256;      // 782 per graph
  const int fillB = degB;

  // one memset: poolrep + ctrs + deg2 (adjacent)
  hipMemsetAsync(poolrep, 0, (16 * 256 + 8 + Ntot) * sizeof(float), stream);

  // D0: weight convert (all 4 matrices, frag order)
  k_wcvt<<<32, 256, 0, stream>>>(W_in[0], W_in[1], W_in[2], W_in[3], WfB);

  // D1: deg_slot (1564 aux) || chained enc1+enc2 (782) -> bufA
  k_d1<<<2 * degB + G1, 256, 0, stream>>>(
      x1, x2, WfB, B_in[0], B_in[1], bufA, ei1, ei2, E, N, Ntot,
      deg2, slot, G1, 2 * degB, degB);

  // D2: deg scan + dis (last block scans partials; 391 fences — measured OK)
  k_scan<<<scanB, 256, 0, stream>>>(deg2, offs, partials, dis, Ntot, scanB, ctrs);

  // D3: fill-g1 || conv1 both graphs (T1 = (H@W3+b3)*dis) -> bufB
  k_gemm_fill<<<fillB + G1, 256, 0, stream>>>(
      bufA, WfB + 2 * 16384, B_in[2], dis, bufB, Ntot, G1,
      0, ei1, ei2, E, N, offs, partials, slot, csr_col, fillB);

  // D4: fill-g2 || agg1-g1 (bufB -> bufC rows [0,N))
  k_agg_fill<<<aggB + fillB, 256, 0, stream>>>(
      bufB, offs, partials, csr_col, dis, bufC, 0, N, Ntot, 2 * E, aggB,
      1, ei1, ei2, E, slot, csr_col, fillB);

  // D5: conv2-g1 (bufC -> bufA rows [0,N)) || agg1-g2 (bufB -> bufC rows [N,2N))
  k_agg_gemm<false><<<aggB + Gc, 256, 0, stream>>>(
      bufB, offs, partials, csr_col, dis, bufC, nullptr, N, N, Ntot, 2 * E, aggB,
      bufC, WfB + 3 * 16384, B_in[3], bufA, 0, Gc);

  // D6: conv2-g2 (bufC -> bufA rows [N,2N)) || agg2-g1 (bufA -> pool, graph 1)
  k_agg_gemm<true><<<aggB + Gc, 256, 0, stream>>>(
      bufA, offs, partials, csr_col, dis, nullptr, poolrep, 0, N, Ntot, 2 * E, aggB,
      bufC, WfB + 3 * 16384, B_in[3], bufA, N, Gc);

  // D7: agg2-g2 (bufA -> pool, graph 2)
  k_agg_pool<<<aggB, 256, 0, stream>>>(
      bufA, offs, partials, csr_col, dis, poolrep, N, N, Ntot, 2 * E);

  // D8: final MLP
  k_final<<<1, 128, 0, stream>>>(poolrep, sim_w1, sim_b1, sim_w2, sim_b2,
                                 (float*)d_out, 1.0f / (float)N);
}

// Round 11
// 404.385 us; speedup vs baseline: 1.5437x; 1.5437x over previous
//
#include <hip/hip_runtime.h>

#define HD 128  // hidden/feature dim (fixed by problem)

typedef _Float16 f16x8 __attribute__((ext_vector_type(8)));
typedef _Float16 f16x2 __attribute__((ext_vector_type(2)));
typedef float f32x4 __attribute__((ext_vector_type(4)));

// sparse role (role=1) occupies every k-th block: positions q*k, q<S.
__device__ __forceinline__ void role_map(int bi, int S, int k, int& role, int& rid) {
  int q = bi / k, rem = bi - q * k;
  if (rem == 0 && q < S) { role = 1; rid = q; }
  else { role = 0; int na = q + (rem ? 1 : 0); if (na > S) na = S; rid = bi - na; }
}

// ---------------- weight convert: fp32 [k][n] -> f16 MFMA-fragment order ----------
__global__ void k_wcvt(const float* __restrict__ w0, const float* __restrict__ w1,
                       const float* __restrict__ w2, const float* __restrict__ w3,
                       _Float16* __restrict__ Wf) {
  int m = blockIdx.x >> 3;
  const float* Wg = (m == 0) ? w0 : (m == 1) ? w1 : (m == 2) ? w2 : w3;
  int idx0 = (blockIdx.x & 7) * 2048 + threadIdx.x * 8;
  float4 u0 = *(const float4*)(Wg + idx0);
  float4 u1 = *(const float4*)(Wg + idx0 + 4);
  int k = idx0 >> 7, n0 = idx0 & 127;
  int kc = k >> 5, q2 = (k >> 3) & 3, j = k & 7;
  _Float16* dst = Wf + (size_t)m * 16384;
  float vv[8] = {u0.x, u0.y, u0.z, u0.w, u1.x, u1.y, u1.z, u1.w};
  #pragma unroll
  for (int d = 0; d < 8; ++d) {
    int n = n0 + d;
    dst[(size_t)(((n >> 4) * 4 + kc) * 64 + 16 * q2 + (n & 15)) * 8 + j] = (_Float16)vv[d];
  }
}

// ---------------- deg+slot role (atomic-rate-bound) ----------------
__device__ __forceinline__ void deg_core(int rid, int degB,
    const int* __restrict__ ei0, const int* __restrict__ ei1, int E, int N,
    int* __restrict__ deg2, unsigned short* __restrict__ slot) {
  int g = (rid >= degB);
  int cb = rid - g * degB;
  const int* rows = g ? ei1 : ei0;
  int* deg = deg2 + g * N;
  unsigned short* sl = slot + (size_t)g * E;
  int base = (cb * 256 + threadIdx.x) * 4;
  if (base + 3 < E) {
    int4 r = *(const int4*)(rows + base);
    union { unsigned short us[4]; uint2 v; } s;
    s.us[0] = (unsigned short)atomicAdd(&deg[r.x], 1);
    s.us[1] = (unsigned short)atomicAdd(&deg[r.y], 1);
    s.us[2] = (unsigned short)atomicAdd(&deg[r.z], 1);
    s.us[3] = (unsigned short)atomicAdd(&deg[r.w], 1);
    *(uint2*)(sl + base) = s.v;
  } else {
    for (int e = base; e < E; ++e)
      sl[e] = (unsigned short)atomicAdd(&deg[rows[e]], 1);
  }
}

// ---------------- CSR fill role (atomic-free; lazy offs); rid spans both graphs ---
__device__ __forceinline__ void fill_core(int rid, int fillB,
    const int* __restrict__ ei0, const int* __restrict__ ei1, int E, int N,
    const int* __restrict__ offs, const int* __restrict__ partials,
    const unsigned short* __restrict__ slot, unsigned short* __restrict__ csr_col) {
  int g = (rid >= fillB);
  int cb = rid - g * fillB;
  const int* eg = (g ? ei1 : ei0);
  const int* ob = offs + g * N;
  const unsigned short* sl = slot + (size_t)g * E;
  int gN = g * N;
  int base = (cb * 256 + threadIdx.x) * 4;
  if (base + 3 < E) {
    int4 r = *(const int4*)(eg + base);
    int4 c = *(const int4*)(eg + E + base);
    uint2 sv = *(const uint2*)(sl + base);
    csr_col[ob[r.x] + partials[(gN + r.x) >> 8] + (sv.x & 0xffff)] = (unsigned short)c.x;
    csr_col[ob[r.y] + partials[(gN + r.y) >> 8] + (sv.x >> 16)]    = (unsigned short)c.y;
    csr_col[ob[r.z] + partials[(gN + r.z) >> 8] + (sv.y & 0xffff)] = (unsigned short)c.z;
    csr_col[ob[r.w] + partials[(gN + r.w) >> 8] + (sv.y >> 16)]    = (unsigned short)c.w;
  } else {
    for (int e = base; e < E; ++e)
      csr_col[ob[eg[e]] + partials[(gN + eg[e]) >> 8] + sl[e]] = (unsigned short)eg[E + e];
  }
}

// ---------------- GEMM role: C = (A @ Wfrag + b) * dis[row] ----------------
// block = 128 rows (4 waves x 32); W staged LDS (conflict-free b128 copy).
__device__ __forceinline__ void gemm_core(_Float16* lds, int bi,
    const _Float16* __restrict__ Ab, const _Float16* __restrict__ Wf,
    const float* __restrict__ bias, const float* __restrict__ scale,
    _Float16* __restrict__ C, int Ntot) {
  const int tid = threadIdx.x;
  #pragma unroll
  for (int i = 0; i < 8; ++i)
    *(float4*)&lds[tid * 8 + i * 2048] = *(const float4*)&Wf[tid * 8 + i * 2048];
  __syncthreads();

  const int lane = tid & 63, wave = tid >> 6;
  const int n16 = lane & 15, q = lane >> 4;
  const int rowbase = bi * 128 + wave * 32;

  int arow[2];
  #pragma unroll
  for (int t = 0; t < 2; ++t) {
    int r = rowbase + 16 * t + n16;
    arow[t] = (r < Ntot) ? r : (Ntot - 1);
  }
  f32x4 acc[2][8];
  #pragma unroll
  for (int t = 0; t < 2; ++t)
    #pragma unroll
    for (int nt = 0; nt < 8; ++nt) acc[t][nt] = (f32x4){0.f, 0.f, 0.f, 0.f};

  #pragma unroll
  for (int kc = 0; kc < 4; ++kc) {
    f16x8 a[2];
    #pragma unroll
    for (int t = 0; t < 2; ++t)
      a[t] = *(const f16x8*)(Ab + (size_t)arow[t] * HD + kc * 32 + q * 8);
    #pragma unroll
    for (int nt = 0; nt < 8; ++nt) {
      f16x8 b = *(const f16x8*)&lds[(size_t)((nt * 4 + kc) * 64 + lane) * 8];
      #pragma unroll
      for (int t = 0; t < 2; ++t)
        acc[t][nt] = __builtin_amdgcn_mfma_f32_16x16x32_f16(a[t], b, acc[t][nt], 0, 0, 0);
    }
  }
  float bv[8];
  #pragma unroll
  for (int nt = 0; nt < 8; ++nt) bv[nt] = bias[nt * 16 + n16];
  #pragma unroll
  for (int t = 0; t < 2; ++t) {
    #pragma unroll
    for (int r = 0; r < 4; ++r) {
      int row = rowbase + 16 * t + 4 * q + r;
      if (row < Ntot) {
        float s = scale[row];
        #pragma unroll
        for (int nt = 0; nt < 8; ++nt) {
          float v = (acc[t][nt][r] + bv[nt]) * s;
          C[(size_t)row * HD + nt * 16 + n16] = (_Float16)v;
        }
      }
    }
  }
}

// ---------------- chained enc1+enc2 (row-local; act via wave-private LDS) ---------
__device__ __forceinline__ void chain_core(_Float16* act, int bi,
    const float* __restrict__ x0, const float* __restrict__ x1,
    const _Float16* __restrict__ Wf0, const _Float16* __restrict__ Wf1,
    const float* __restrict__ b1, const float* __restrict__ b2,
    _Float16* __restrict__ H, int N, int Ntot) {
  const int tid = threadIdx.x;
  const int lane = tid & 63, wave = tid >> 6;
  const int n16 = lane & 15, q = lane >> 4;
  const int rowbase = bi * 128 + wave * 32;
  _Float16* wact = act + wave * 4352;   // 32 rows x 136 f16

  int arow[2];
  #pragma unroll
  for (int t = 0; t < 2; ++t) {
    int r = rowbase + 16 * t + n16;
    arow[t] = (r < Ntot) ? r : (Ntot - 1);
  }
  f32x4 acc[2][8];
  #pragma unroll
  for (int t = 0; t < 2; ++t)
    #pragma unroll
    for (int nt = 0; nt < 8; ++nt) acc[t][nt] = (f32x4){0.f, 0.f, 0.f, 0.f};

  // layer 1: x -> relu(x@W1+b1) -> wave-private LDS
  #pragma unroll
  for (int kc = 0; kc < 4; ++kc) {
    f16x8 a[2];
    #pragma unroll
    for (int t = 0; t < 2; ++t) {
      int r = arow[t];
      const float* src = (r < N) ? (x0 + (size_t)r * HD) : (x1 + (size_t)(r - N) * HD);
      float4 u0 = *(const float4*)(src + kc * 32 + q * 8);
      float4 u1 = *(const float4*)(src + kc * 32 + q * 8 + 4);
      union { _Float16 h[8]; f16x8 v; } tmp;
      tmp.h[0] = (_Float16)u0.x; tmp.h[1] = (_Float16)u0.y;
      tmp.h[2] = (_Float16)u0.z; tmp.h[3] = (_Float16)u0.w;
      tmp.h[4] = (_Float16)u1.x; tmp.h[5] = (_Float16)u1.y;
      tmp.h[6] = (_Float16)u1.z; tmp.h[7] = (_Float16)u1.w;
      a[t] = tmp.v;
    }
    #pragma unroll
    for (int nt = 0; nt < 8; ++nt) {
      f16x8 b = *(const f16x8*)&Wf0[(size_t)((nt * 4 + kc) * 64 + lane) * 8];
      #pragma unroll
      for (int t = 0; t < 2; ++t)
        acc[t][nt] = __builtin_amdgcn_mfma_f32_16x16x32_f16(a[t], b, acc[t][nt], 0, 0, 0);
    }
  }
  {
    float bv[8];
    #pragma unroll
    for (int nt = 0; nt < 8; ++nt) bv[nt] = b1[nt * 16 + n16];
    #pragma unroll
    for (int t = 0; t < 2; ++t)
      #pragma unroll
      for (int r = 0; r < 4; ++r)
        #pragma unroll
        for (int nt = 0; nt < 8; ++nt)
          wact[(16 * t + 4 * q + r) * 136 + nt * 16 + n16] =
              (_Float16)fmaxf(acc[t][nt][r] + bv[nt], 0.f);
  }

  // layer 2: h1 -> h1@W2+b2 (no relu)
  #pragma unroll
  for (int t = 0; t < 2; ++t)
    #pragma unroll
    for (int nt = 0; nt < 8; ++nt) acc[t][nt] = (f32x4){0.f, 0.f, 0.f, 0.f};
  #pragma unroll
  for (int kc = 0; kc < 4; ++kc) {
    f16x8 a[2];
    #pragma unroll
    for (int t = 0; t < 2; ++t)
      a[t] = *(const f16x8*)&wact[(16 * t + n16) * 136 + kc * 32 + q * 8];
    #pragma unroll
    for (int nt = 0; nt < 8; ++nt) {
      f16x8 b = *(const f16x8*)&Wf1[(size_t)((nt * 4 + kc) * 64 + lane) * 8];
      #pragma unroll
      for (int t = 0; t < 2; ++t)
        acc[t][nt] = __builtin_amdgcn_mfma_f32_16x16x32_f16(a[t], b, acc[t][nt], 0, 0, 0);
    }
  }
  {
    float bv[8];
    #pragma unroll
    for (int nt = 0; nt < 8; ++nt) bv[nt] = b2[nt * 16 + n16];
    #pragma unroll
    for (int t = 0; t < 2; ++t)
      #pragma unroll
      for (int r = 0; r < 4; ++r) {
        int row = rowbase + 16 * t + 4 * q + r;
        if (row < Ntot)
          #pragma unroll
          for (int nt = 0; nt < 8; ++nt)
            H[(size_t)row * HD + nt * 16 + n16] = (_Float16)(acc[t][nt][r] + bv[nt]);
      }
  }
}

// ---------------- aggregate core: out[r] = relu(dis[r]*sum T[col]) ----------------
// one wave/node over BOTH graphs (gw in [0,Ntot)); 16 lanes/row, uint4/lane.
template<bool POOL>
__device__ __forceinline__ void agg_core(float* red, int rid,
    const _Float16* __restrict__ T, const int* __restrict__ offs,
    const int* __restrict__ partials, const unsigned short* __restrict__ csr_col,
    const float* __restrict__ dis, _Float16* __restrict__ out,
    float* __restrict__ poolrep, int N, int Ntot, int Etot) {
  const int lane = threadIdx.x & 63;
  const int wave = threadIdx.x >> 6;
  const int gw = rid * 4 + wave;
  const int sub = lane >> 4, c16 = lane & 15;

  f16x2 hacc[4];
  #pragma unroll
  for (int j = 0; j < 4; ++j) hacc[j] = (f16x2){(_Float16)0.f, (_Float16)0.f};

  const int beg = offs[gw] + partials[gw >> 8];
  const int end = (gw + 1 == Ntot) ? Etot : (offs[gw + 1] + partials[(gw + 1) >> 8]);
  const uint4* Tg = (const uint4*)(T + (size_t)(gw >= N ? N : 0) * HD);
  for (int e = beg; e < end; e += 16) {
    uint4 v[4];
    #pragma unroll
    for (int gp = 0; gp < 4; ++gp) {
      v[gp] = make_uint4(0, 0, 0, 0);
      if (e + 4 * gp < end) {              // wave-uniform
        int eg = e + 4 * gp + sub;
        bool valid = (eg < end);
        int ce = valid ? eg : (end - 1);
        int col = csr_col[ce];
        uint4 tv = Tg[(size_t)col * 16 + c16];
        if (valid) v[gp] = tv;
      }
    }
    #pragma unroll
    for (int gp = 0; gp < 4; ++gp) {
      union { uint4 u; f16x2 h[4]; } w;
      w.u = v[gp];
      hacc[0] += w.h[0];
      hacc[1] += w.h[1];
      hacc[2] += w.h[2];
      hacc[3] += w.h[3];
    }
  }

  float ax[8];
  #pragma unroll
  for (int j = 0; j < 4; ++j) {
    ax[2 * j]     = (float)hacc[j][0];
    ax[2 * j + 1] = (float)hacc[j][1];
  }
  #pragma unroll
  for (int j = 0; j < 8; ++j) {
    ax[j] += __shfl_xor(ax[j], 32, 64);
    ax[j] += __shfl_xor(ax[j], 16, 64);
  }
  float dr = dis[gw];
  #pragma unroll
  for (int j = 0; j < 8; ++j) ax[j] = fmaxf(ax[j] * dr, 0.f);

  if (!POOL) {
    if (sub == 0) {
      union { uint4 u; _Float16 h[8]; } o;
      #pragma unroll
      for (int j = 0; j < 8; ++j) o.h[j] = (_Float16)ax[j];
      ((uint4*)out)[(size_t)gw * 16 + c16] = o.u;
    }
  } else {
    if (sub == 0) {
      *(float4*)&red[wave * 128 + c16 * 8]     = make_float4(ax[0], ax[1], ax[2], ax[3]);
      *(float4*)&red[wave * 128 + c16 * 8 + 4] = make_float4(ax[4], ax[5], ax[6], ax[7]);
    }
    __syncthreads();
    int t = threadIdx.x;
    if (t < 128) {
      float s = red[t] + red[128 + t] + red[256 + t] + red[384 + t];
      int g = (rid * 4 >= N) ? 1 : 0;          // N % 4 == 0: block never spans graphs
      atomicAdd(&poolrep[(size_t)((rid & 15) * 2 + g) * 128 + t], s);
    }
  }
}

// ---------------- D1: deg_slot aux || chained enc1+enc2 ----------------
__global__ __launch_bounds__(256, 4) void k_d1(
    const float* __restrict__ x0, const float* __restrict__ x1,
    const _Float16* __restrict__ Wf, const float* __restrict__ b1,
    const float* __restrict__ b2, _Float16* __restrict__ H,
    const int* __restrict__ ei0, const int* __restrict__ ei1, int E, int N, int Ntot,
    int* __restrict__ deg2, unsigned short* __restrict__ slot, int G, int A, int degB) {
  __shared__ _Float16 act[4 * 4352];  // 34.8 KB
  int role, rid;
  role_map(blockIdx.x, G, (A + G) / G, role, rid);  // sparse = chain (every 3rd)
  if (role == 1)
    chain_core(act, rid, x0, x1, Wf, Wf + 16384, b1, b2, H, N, Ntot);
  else
    deg_core(rid, degB, ei0, ei1, E, N, deg2, slot);
}

// ---------------- D2: per-block deg scan + dis; last block scans partials ---------
__global__ __launch_bounds__(256, 2) void k_scan(
    const int* __restrict__ deg2, int* __restrict__ offs, int* __restrict__ partials,
    float* __restrict__ dis, int Ntot, int scanB, int* __restrict__ ctr) {
  __shared__ int s[512];
  __shared__ int lastFlag;
  int rid = blockIdx.x, t = threadIdx.x;
  int i = rid * 256 + t;
  int v = (i < Ntot) ? deg2[i] : 0;
  s[t] = v;
  __syncthreads();
  #pragma unroll
  for (int off = 1; off < 256; off <<= 1) {
    int x = (t >= off) ? s[t - off] : 0;
    __syncthreads();
    s[t] += x;
    __syncthreads();
  }
  if (i < Ntot) {
    offs[i] = s[t] - v;
    dis[i] = (v > 0) ? (1.0f / sqrtf((float)v)) : 0.0f;
  }
  if (t == 255) partials[rid] = s[255];
  __syncthreads();
  if (t == 0) {
    __threadfence();
    lastFlag = (atomicAdd(ctr, 1) == scanB - 1);
  }
  __syncthreads();
  if (lastFlag) {
    __threadfence();
    volatile int* vp = partials;
    int P = scanB;
    int v0 = (t < P) ? vp[t] : 0;
    int v1 = (t + 256 < P) ? vp[t + 256] : 0;
    __syncthreads();
    s[t] = v0;
    s[t + 256] = v1;
    __syncthreads();
    #pragma unroll
    for (int off = 1; off < 256; off <<= 1) {
      int x0 = (t >= off) ? s[t - off] : 0;
      int x1 = (t >= off) ? s[256 + t - off] : 0;
      __syncthreads();
      s[t] += x0;
      s[256 + t] += x1;
      __syncthreads();
    }
    int tot0 = s[255];
    if (t < P) partials[t] = s[t] - v0;
    if (t + 256 < P) partials[t + 256] = s[256 + t] + tot0 - v1;
  }
}

// ---------------- D3: conv1 both (sparse) || CSR fill both graphs ----------------
__global__ __launch_bounds__(256, 4) void k_conv1_fill(
    const _Float16* __restrict__ Ain, const _Float16* __restrict__ Wf,
    const float* __restrict__ bias, const float* __restrict__ dis,
    _Float16* __restrict__ Cout, int Ntot, int G,
    const int* __restrict__ ei0, const int* __restrict__ ei1, int E, int N,
    const int* __restrict__ offs, const int* __restrict__ partials,
    const unsigned short* __restrict__ slot, unsigned short* __restrict__ csr_col,
    int fillB) {
  __shared__ _Float16 lds[16384];
  int role, rid;
  role_map(blockIdx.x, G, 3, role, rid);  // sparse = gemm (G = fillB, 2*fillB + G blocks)
  if (role == 1)
    gemm_core(lds, rid, Ain, Wf, bias, dis, Cout, Ntot);
  else
    fill_core(rid, fillB, ei0, ei1, E, N, offs, partials, slot, csr_col);
}

// ---------------- D4: aggregate both graphs (no pool; small LDS, high occ) --------
__global__ __launch_bounds__(256) void k_agg(
    const _Float16* __restrict__ T, const int* __restrict__ offs,
    const int* __restrict__ partials, const unsigned short* __restrict__ csr_col,
    const float* __restrict__ dis, _Float16* __restrict__ out, int N, int Ntot, int Etot) {
  agg_core<false>(nullptr, blockIdx.x, T, offs, partials, csr_col, dis,
                  out, nullptr, N, Ntot, Etot);
}

// ---------------- D5: conv2 GEMM both graphs (standalone) ----------------
__global__ __launch_bounds__(256, 4) void k_gemm(
    const _Float16* __restrict__ Ain, const _Float16* __restrict__ Wf,
    const float* __restrict__ bias, const float* __restrict__ dis,
    _Float16* __restrict__ Cout, int Ntot) {
  __shared__ _Float16 lds[16384];
  gemm_core(lds, blockIdx.x, Ain, Wf, bias, dis, Cout, Ntot);
}

// ---------------- D6: aggregate + pool both graphs (small LDS, high occ) ----------
__global__ __launch_bounds__(256) void k_agg_pool(
    const _Float16* __restrict__ T, const int* __restrict__ offs,
    const int* __restrict__ partials, const unsigned short* __restrict__ csr_col,
    const float* __restrict__ dis, float* __restrict__ poolrep,
    int N, int Ntot, int Etot) {
  __shared__ float red[512];
  agg_core<true>(red, blockIdx.x, T, offs, partials, csr_col, dis,
                 nullptr, poolrep, N, Ntot, Etot);
}

// ---------------- final similarity MLP (tiny, fp32) ----------------
__global__ void k_final(const float* __restrict__ poolrep,
                        const float* __restrict__ W1, const float* __restrict__ b1,
                        const float* __restrict__ W2, const float* __restrict__ b2,
                        float* __restrict__ out, float invN) {
  __shared__ float cs[512];
  __shared__ float red[2];
  int t = threadIdx.x;  // 128 threads
  float g1 = 0.f, g2 = 0.f;
  #pragma unroll
  for (int r = 0; r < 16; ++r) {
    g1 += poolrep[r * 256 + t];
    g2 += poolrep[r * 256 + 128 + t];
  }
  g1 *= invN;
  g2 *= invN;
  cs[t] = g1;
  cs[128 + t] = g2;
  cs[256 + t] = fabsf(g1 - g2);
  cs[384 + t] = g1 * g2;
  __syncthreads();
  float acc = b1[t];
  #pragma unroll 8
  for (int i = 0; i < 512; ++i) acc = fmaf(cs[i], W1[(size_t)i * HD + t], acc);
  float h = fmaxf(acc, 0.f);
  float v = h * W2[t];
  #pragma unroll
  for (int off = 32; off > 0; off >>= 1) v += __shfl_down(v, off, 64);
  if ((t & 63) == 0) red[t >> 6] = v;
  __syncthreads();
  if (t == 0) out[0] = red[0] + red[1] + b2[0];
}

extern "C" void kernel_launch(void* const* d_in, const int* in_sizes, int n_in,
                              void* d_out, int out_size, void* d_ws, size_t ws_size,
                              hipStream_t stream) {
  const float* x1     = (const float*)d_in[0];
  const int*   ei1    = (const int*)d_in[1];
  const float* x2     = (const float*)d_in[2];
  const int*   ei2    = (const int*)d_in[3];
  const float* W_in[4] = {(const float*)d_in[4], (const float*)d_in[6],
                          (const float*)d_in[8], (const float*)d_in[10]};
  const float* B_in[4] = {(const float*)d_in[5], (const float*)d_in[7],
                          (const float*)d_in[9], (const float*)d_in[11]};
  const float* sim_w1 = (const float*)d_in[12];
  const float* sim_b1 = (const float*)d_in[13];
  const float* sim_w2 = (const float*)d_in[14];
  const float* sim_b2 = (const float*)d_in[15];

  const int N = in_sizes[0] / HD;
  const int E = in_sizes[1] / 2;
  const int Ntot = 2 * N;

  // workspace layout (16B-aligned chunks first)
  _Float16* sp = (_Float16*)d_ws;
  _Float16* bufA = sp; sp += (size_t)Ntot * HD;   // H (enc out), later T2 (conv2 out)
  _Float16* bufB = sp; sp += (size_t)Ntot * HD;   // T1 (conv1 out)
  _Float16* bufC = sp; sp += (size_t)Ntot * HD;   // H1 (agg1 out)
  _Float16* WfB  = sp; sp += 4 * 16384;           // enc1,enc2,conv1,conv2 frag f16
  float* fp = (float*)sp;
  float* dis     = fp; fp += Ntot;
  float* poolrep = fp; fp += 16 * 256;            // zeroed with ctrs+deg2 (adjacent)
  int* ip = (int*)fp;
  int* ctrs     = ip; ip += 8;                    // [0]=pscan ctr
  int* deg2     = ip; ip += Ntot;
  int* offs     = ip; ip += Ntot;
  int* partials = ip; ip += 512;
  ip = (int*)(((uintptr_t)ip + 15) & ~(uintptr_t)15);
  unsigned short* slot = (unsigned short*)ip;       // 2E ushorts
  unsigned short* csr_col = slot + 2 * (size_t)E;   // 2E ushorts

  const int G1    = (Ntot + 127) / 128;             // 782 chain/conv GEMM blocks
  const int scanB = (Ntot + 255) / 256;             // 391 (<=512 required)
  const int aggB  = Ntot / 4;                       // 25000 (Ntot % 4 == 0)
  const int degB  = ((E + 3) / 4 + 255) / 256;      // 782 per graph
  const int fillB = degB;

  // one memset: poolrep + ctrs + deg2 (adjacent)
  hipMemsetAsync(poolrep, 0, (16 * 256 + 8 + Ntot) * sizeof(float), stream);

  // D0: weight convert (all 4 matrices, frag order)
  k_wcvt<<<32, 256, 0, stream>>>(W_in[0], W_in[1], W_in[2], W_in[3], WfB);

  // D1: deg_slot (1564 aux) || chained enc1+enc2 (782) -> bufA
  k_d1<<<2 * degB + G1, 256, 0, stream>>>(
      x1, x2, WfB, B_in[0], B_in[1], bufA, ei1, ei2, E, N, Ntot,
      deg2, slot, G1, 2 * degB, degB);

  // D2: deg scan + dis (last block scans partials; 391 fences — measured OK)
  k_scan<<<scanB, 256, 0, stream>>>(deg2, offs, partials, dis, Ntot, scanB, ctrs);

  // D3: conv1 both (sparse, T1 = (H@W3+b3)*dis -> bufB) || fill both graphs
  k_conv1_fill<<<2 * fillB + G1, 256, 0, stream>>>(
      bufA, WfB + 2 * 16384, B_in[2], dis, bufB, Ntot, G1,
      ei1, ei2, E, N, offs, partials, slot, csr_col, fillB);

  // D4: aggregate 1 both graphs (bufB -> bufC); occupancy-critical, standalone
  k_agg<<<aggB, 256, 0, stream>>>(bufB, offs, partials, csr_col, dis, bufC, N, Ntot, 2 * E);

  // D5: conv2 both graphs (T2 = (H1@W4+b4)*dis -> bufA)
  k_gemm<<<G1, 256, 0, stream>>>(bufC, WfB + 3 * 16384, B_in[3], dis, bufA, Ntot);

  // D6: aggregate 2 + pool both graphs (bufA -> poolrep); standalone
  k_agg_pool<<<aggB, 256, 0, stream>>>(bufA, offs, partials, csr_col, dis, poolrep,
                                       N, Ntot, 2 * E);

  // D7: final MLP
  k_final<<<1, 128, 0, stream>>>(poolrep, sim_w1, sim_b1, sim_w2, sim_b2,
                                 (float*)d_out, 1.0f / (float)N);
}